// Round 5
// baseline (780.418 us; speedup 1.0000x reference)
//
#include <hip/hip_runtime.h>

// Problem constants (match reference)
constexpr int NN = 50000;      // nodes
constexpr int NE = 800000;     // edges
constexpr int F_IN = 128;
constexpr int D0 = 256;
constexpr int D1 = 64;
constexpr int NG = 256;        // graphs
constexpr float EPS_BN = 1e-5f;

typedef __attribute__((ext_vector_type(8))) short bf16x8;
typedef __attribute__((ext_vector_type(4))) float f32x4;
typedef __attribute__((ext_vector_type(8))) ushort u16x8;
typedef __attribute__((ext_vector_type(4))) ushort u16x4;

__device__ inline ushort f2bf(float f) {
    uint32_t u = __float_as_uint(f);
    uint32_t r = u + 0x7fff + ((u >> 16) & 1);   // RNE
    return (ushort)(r >> 16);
}
__device__ inline float bf2f(ushort b) {
    return __uint_as_float((uint32_t)b << 16);
}

// ---- DPP 16-lane sum: quad_perm xor1, xor2, row_ror:4, row_ror:8 (pure VALU) ----
template<int CTRL>
__device__ __forceinline__ float dpp_add(float x) {
    int t = __builtin_amdgcn_update_dpp(0, __float_as_int(x), CTRL, 0xF, 0xF, true);
    return x + __int_as_float(t);
}
__device__ __forceinline__ float red16(float x) {
    x = dpp_add<0xB1>(x);    // quad_perm [1,0,3,2]  (xor 1)
    x = dpp_add<0x4E>(x);    // quad_perm [2,3,0,1]  (xor 2)
    x = dpp_add<0x124>(x);   // row_ror:4
    x = dpp_add<0x128>(x);   // row_ror:8
    return x;
}

// ---------------- edge sort (counting sort by dst) ----------------
__global__ __launch_bounds__(256) void k_hist(const int* __restrict__ ei, int* __restrict__ cnt) {
    int e = blockIdx.x * 256 + threadIdx.x;
    if (e < NE) atomicAdd(&cnt[ei[NE + e]], 1);
}

__global__ __launch_bounds__(256) void k_scan1(const int* __restrict__ cnt,
                                               int* __restrict__ offs,
                                               int* __restrict__ bsum) {
    __shared__ int lds[256];
    int idx = blockIdx.x * 256 + threadIdx.x;
    int v = (idx < NN) ? cnt[idx] : 0;
    lds[threadIdx.x] = v;
    __syncthreads();
    #pragma unroll
    for (int off = 1; off < 256; off <<= 1) {
        int add = (threadIdx.x >= off) ? lds[threadIdx.x - off] : 0;
        __syncthreads();
        lds[threadIdx.x] += add;
        __syncthreads();
    }
    if (idx < NN) offs[idx] = lds[threadIdx.x] - v;
    if (threadIdx.x == 255) bsum[blockIdx.x] = lds[255];
}

__global__ __launch_bounds__(256) void k_scan2(const int* __restrict__ bsum,
                                               int* __restrict__ boff, int nblk) {
    __shared__ int lds[256];
    int v = (threadIdx.x < nblk) ? bsum[threadIdx.x] : 0;
    lds[threadIdx.x] = v;
    __syncthreads();
    #pragma unroll
    for (int off = 1; off < 256; off <<= 1) {
        int add = (threadIdx.x >= off) ? lds[threadIdx.x - off] : 0;
        __syncthreads();
        lds[threadIdx.x] += add;
        __syncthreads();
    }
    if (threadIdx.x < nblk) boff[threadIdx.x] = lds[threadIdx.x] - v;
}

__global__ __launch_bounds__(256) void k_scan3(int* __restrict__ offs,
                                               const int* __restrict__ boff,
                                               int* __restrict__ cursor) {
    int idx = blockIdx.x * 256 + threadIdx.x;
    if (idx < NN) {
        int o = offs[idx] + boff[blockIdx.x];
        offs[idx] = o;
        cursor[idx] = o;
    }
    if (idx == 0) offs[NN] = NE;
}

// pack (src, edge_attr bits) per sorted edge
__global__ __launch_bounds__(256) void k_scatter(const int* __restrict__ ei,
                                                 const float* __restrict__ ea,
                                                 int* __restrict__ cursor,
                                                 int2* __restrict__ sedge) {
    int e = blockIdx.x * 256 + threadIdx.x;
    if (e < NE) {
        int d = ei[NE + e];
        int pos = atomicAdd(&cursor[d], 1);
        sedge[pos] = make_int2(ei[e], __float_as_int(ea[e]));
    }
}

// ---------------- prep: fp32 -> bf16 cast (vectorized) ----------------
__global__ __launch_bounds__(256) void k_f2bf4(const float* __restrict__ in,
                                               ushort* __restrict__ out, int n4) {
    for (int i = blockIdx.x * 256 + threadIdx.x; i < n4; i += gridDim.x * 256) {
        float4 v = *reinterpret_cast<const float4*>(&in[(size_t)i * 4]);
        ushort4 o;
        o.x = f2bf(v.x); o.y = f2bf(v.y); o.z = f2bf(v.z); o.w = f2bf(v.w);
        *reinterpret_cast<ushort4*>(&out[(size_t)i * 4]) = o;
    }
}

// ---------------- prep: weight transpose + bf16 ([K][D] -> [D][K]) ----------------
struct WPrep {
    const float* src[8];
    ushort* dst[8];
    int K[8];
    int D[8];
};
__global__ __launch_bounds__(256) void k_wprep(WPrep p) {
    int m = blockIdx.y;
    int K = p.K[m], D = p.D[m];
    int n = K * D;
    for (int idx = blockIdx.x * 256 + threadIdx.x; idx < n; idx += gridDim.x * 256) {
        int c = idx / K, k = idx - c * K;
        p.dst[m][idx] = f2bf(p.src[m][(size_t)k * D + c]);
    }
}

// ---------------- fused 4-matrix MFMA GEMM ----------------
// mat0 -> Oq (fp32); mat1 -> kv[:, 0:DOUT] (bf16); mat2 -> kv[:, DOUT:2*DOUT]; mat3 -> Oh (fp32).
template<int K, int DOUT>
__global__ __launch_bounds__(256) void k_gemm_mfma(
    const ushort* __restrict__ Xb, const ushort* __restrict__ Wt,
    const float* __restrict__ B0, const float* __restrict__ B1,
    const float* __restrict__ B2, const float* __restrict__ B3,
    float* __restrict__ Oq, ushort* __restrict__ Okv,
    float* __restrict__ Oh)
{
    constexpr int BM = 128, BN = 64, BK = 32;
    __shared__ ushort Xs[BM][BK + 8];
    __shared__ ushort Wss[BN][BK + 8];

    int row0 = blockIdx.x * BM;
    int col0 = blockIdx.y * BN;
    int mat = col0 / DOUT;
    int mcol0 = col0 - mat * DOUT;
    const float* Bb = (mat == 0) ? B0 : (mat == 1) ? B1 : (mat == 2) ? B2 : B3;

    int t = threadIdx.x;
    int wid = t >> 6, lane = t & 63;
    int wr = wid >> 1, wc = wid & 1;
    int lr = lane & 15, lk = lane >> 4;

    f32x4 acc[4][2] = {};

    for (int k0 = 0; k0 < K; k0 += BK) {
        #pragma unroll
        for (int i = 0; i < 2; ++i) {
            int slot = t + i * 256;
            int r = slot >> 2, c8 = slot & 3;
            int gr = row0 + r;
            uint4 val = make_uint4(0, 0, 0, 0);
            if (gr < NN) val = *reinterpret_cast<const uint4*>(&Xb[(size_t)gr * K + k0 + c8 * 8]);
            *reinterpret_cast<uint4*>(&Xs[r][c8 * 8]) = val;
        }
        {
            int r = t >> 2, c8 = t & 3;
            uint4 val = *reinterpret_cast<const uint4*>(&Wt[(size_t)(col0 + r) * K + k0 + c8 * 8]);
            *reinterpret_cast<uint4*>(&Wss[r][c8 * 8]) = val;
        }
        __syncthreads();
        bf16x8 a[4], b[2];
        #pragma unroll
        for (int m = 0; m < 4; ++m)
            a[m] = *reinterpret_cast<const bf16x8*>(&Xs[wr * 64 + m * 16 + lr][lk * 8]);
        #pragma unroll
        for (int n = 0; n < 2; ++n)
            b[n] = *reinterpret_cast<const bf16x8*>(&Wss[wc * 32 + n * 16 + lr][lk * 8]);
        #pragma unroll
        for (int m = 0; m < 4; ++m)
            #pragma unroll
            for (int n = 0; n < 2; ++n)
                acc[m][n] = __builtin_amdgcn_mfma_f32_16x16x32_bf16(a[m], b[n], acc[m][n], 0, 0, 0);
        __syncthreads();
    }

    #pragma unroll
    for (int m = 0; m < 4; ++m) {
        #pragma unroll
        for (int n = 0; n < 2; ++n) {
            int gcol = mcol0 + wc * 32 + n * 16 + lr;
            float bias = Bb[gcol];
            #pragma unroll
            for (int r = 0; r < 4; ++r) {
                int grow = row0 + wr * 64 + m * 16 + lk * 4 + r;
                if (grow >= NN) continue;
                float vv = acc[m][n][r] + bias;
                if (mat == 0) Oq[(size_t)grow * DOUT + gcol] = vv;
                else if (mat == 1) Okv[(size_t)grow * (2 * DOUT) + gcol] = f2bf(vv);
                else if (mat == 2) Okv[(size_t)grow * (2 * DOUT) + DOUT + gcol] = f2bf(vv);
                else Oh[(size_t)grow * DOUT + gcol] = vv;
            }
        }
    }
}

// ---------------- per-node attention: 4 edges/wave, DPP-only in-loop reduce ----------------
// logits = (q.k + e*(q.We)) * scale ; out = (sum p*v + (sum p*e)*We) / sum p
// 4 groups x 16 lanes. D=256: 16 dims/lane; D=64: 4 dims/lane.
// 3-stage rotating register pipeline (2 prefetches in flight).
template<int D>
__global__ __launch_bounds__(256) void k_attn(
    const float* __restrict__ q, const ushort* __restrict__ kvb,
    const float* __restrict__ We,
    const int2* __restrict__ sedge,
    const int* __restrict__ offs,
    float* __restrict__ hout)               // pre-loaded with skip; += attn out
{
    int wave = threadIdx.x >> 6;
    int lane = threadIdx.x & 63;
    int node = blockIdx.x * 4 + wave;
    if (node >= NN) return;
    int start = offs[node], stop = offs[node + 1];
    int g = lane >> 4, sl = lane & 15;

    if constexpr (D == 256) {
        constexpr float scale = 0.0625f;
        float q16[16];
        #pragma unroll
        for (int i = 0; i < 4; ++i) {
            float4 tq = *reinterpret_cast<const float4*>(&q[(size_t)node * 256 + sl * 16 + i * 4]);
            q16[i * 4 + 0] = tq.x; q16[i * 4 + 1] = tq.y;
            q16[i * 4 + 2] = tq.z; q16[i * 4 + 3] = tq.w;
        }
        float qWe;
        {
            float s = 0.f;
            #pragma unroll
            for (int i = 0; i < 4; ++i) {
                float4 w = *reinterpret_cast<const float4*>(&We[sl * 16 + i * 4]);
                s = fmaf(q16[i * 4 + 0], w.x, s);
                s = fmaf(q16[i * 4 + 1], w.y, s);
                s = fmaf(q16[i * 4 + 2], w.z, s);
                s = fmaf(q16[i * 4 + 3], w.w, s);
            }
            qWe = red16(s);
        }

        int niter = (stop - start + 3) >> 2;
        float acc16[16] = {};
        float ssum = 0.f, sse = 0.f;

        bool val0, val1; int2 se0, se1;
        u16x8 ka0, kb0, va0, vb0, ka1, kb1, va1, vb1;
        auto LOAD = [&](int j, bool& val, int2& se,
                        u16x8& ka, u16x8& kb, u16x8& va, u16x8& vb) {
            int idx = start + 4 * j + g;
            val = idx < stop;
            int e = val ? idx : 0;
            se = sedge[e];
            const ushort* base = &kvb[(size_t)se.x * 512 + sl * 16];
            ka = *reinterpret_cast<const u16x8*>(base);
            kb = *reinterpret_cast<const u16x8*>(base + 8);
            va = *reinterpret_cast<const u16x8*>(base + 256);
            vb = *reinterpret_cast<const u16x8*>(base + 264);
        };
        LOAD(0, val0, se0, ka0, kb0, va0, vb0);
        LOAD(1, val1, se1, ka1, kb1, va1, vb1);

        for (int j = 0; j < niter; ++j) {
            bool val2; int2 se2; u16x8 ka2, kb2, va2, vb2;
            LOAD(j + 2, val2, se2, ka2, kb2, va2, vb2);
            float dot = 0.f;
            #pragma unroll
            for (int c = 0; c < 8; ++c) dot = fmaf(q16[c], bf2f((ushort)ka0[c]), dot);
            #pragma unroll
            for (int c = 0; c < 8; ++c) dot = fmaf(q16[8 + c], bf2f((ushort)kb0[c]), dot);
            dot = red16(dot);
            float eav = __int_as_float(se0.y);
            float p = val0 ? __expf((dot + eav * qWe) * scale) : 0.f;
            ssum += p;
            sse = fmaf(p, eav, sse);
            #pragma unroll
            for (int c = 0; c < 8; ++c) acc16[c] = fmaf(p, bf2f((ushort)va0[c]), acc16[c]);
            #pragma unroll
            for (int c = 0; c < 8; ++c) acc16[8 + c] = fmaf(p, bf2f((ushort)vb0[c]), acc16[8 + c]);
            val0 = val1; se0 = se1; ka0 = ka1; kb0 = kb1; va0 = va1; vb0 = vb1;
            val1 = val2; se1 = se2; ka1 = ka2; kb1 = kb2; va1 = va2; vb1 = vb2;
        }

        // cross-group combine (once per node)
        ssum += __shfl_xor(ssum, 16); ssum += __shfl_xor(ssum, 32);
        sse  += __shfl_xor(sse, 16);  sse  += __shfl_xor(sse, 32);
        #pragma unroll
        for (int c = 0; c < 16; ++c) {
            acc16[c] += __shfl_xor(acc16[c], 16);
            acc16[c] += __shfl_xor(acc16[c], 32);
        }
        float inv = 1.0f / (ssum + 1e-16f);
        float sel[4];
        #pragma unroll
        for (int c = 0; c < 4; ++c) {
            float a = acc16[c];
            a = (g == 1) ? acc16[4 + c] : a;
            a = (g == 2) ? acc16[8 + c] : a;
            a = (g == 3) ? acc16[12 + c] : a;
            sel[c] = a;
        }
        float4 wq = *reinterpret_cast<const float4*>(&We[sl * 16 + g * 4]);
        float* hp = &hout[(size_t)node * 256 + sl * 16 + g * 4];
        float4 cur = *reinterpret_cast<float4*>(hp);
        cur.x += (sel[0] + sse * wq.x) * inv;
        cur.y += (sel[1] + sse * wq.y) * inv;
        cur.z += (sel[2] + sse * wq.z) * inv;
        cur.w += (sel[3] + sse * wq.w) * inv;
        *reinterpret_cast<float4*>(hp) = cur;
    } else {
        constexpr float scale = 0.125f;
        float q4[4];
        {
            float4 qa = *reinterpret_cast<const float4*>(&q[(size_t)node * 64 + sl * 4]);
            q4[0] = qa.x; q4[1] = qa.y; q4[2] = qa.z; q4[3] = qa.w;
        }
        float qWe;
        {
            float4 w = *reinterpret_cast<const float4*>(&We[sl * 4]);
            float s = q4[0] * w.x + q4[1] * w.y + q4[2] * w.z + q4[3] * w.w;
            qWe = red16(s);
        }

        int niter = (stop - start + 3) >> 2;
        float acc4[4] = {};
        float ssum = 0.f, sse = 0.f;

        bool val0, val1; int2 se0, se1;
        u16x4 ku0, vu0, ku1, vu1;
        auto LOAD = [&](int j, bool& val, int2& se, u16x4& ku, u16x4& vu) {
            int idx = start + 4 * j + g;
            val = idx < stop;
            int e = val ? idx : 0;
            se = sedge[e];
            const ushort* base = &kvb[(size_t)se.x * 128 + sl * 4];
            ku = *reinterpret_cast<const u16x4*>(base);
            vu = *reinterpret_cast<const u16x4*>(base + 64);
        };
        LOAD(0, val0, se0, ku0, vu0);
        LOAD(1, val1, se1, ku1, vu1);

        for (int j = 0; j < niter; ++j) {
            bool val2; int2 se2; u16x4 ku2, vu2;
            LOAD(j + 2, val2, se2, ku2, vu2);
            float dot = 0.f;
            #pragma unroll
            for (int c = 0; c < 4; ++c) dot = fmaf(q4[c], bf2f((ushort)ku0[c]), dot);
            dot = red16(dot);
            float eav = __int_as_float(se0.y);
            float p = val0 ? __expf((dot + eav * qWe) * scale) : 0.f;
            ssum += p;
            sse = fmaf(p, eav, sse);
            #pragma unroll
            for (int c = 0; c < 4; ++c) acc4[c] = fmaf(p, bf2f((ushort)vu0[c]), acc4[c]);
            val0 = val1; se0 = se1; ku0 = ku1; vu0 = vu1;
            val1 = val2; se1 = se2; ku1 = ku2; vu1 = vu2;
        }

        ssum += __shfl_xor(ssum, 16); ssum += __shfl_xor(ssum, 32);
        sse  += __shfl_xor(sse, 16);  sse  += __shfl_xor(sse, 32);
        #pragma unroll
        for (int c = 0; c < 4; ++c) {
            acc4[c] += __shfl_xor(acc4[c], 16);
            acc4[c] += __shfl_xor(acc4[c], 32);
        }
        float inv = 1.0f / (ssum + 1e-16f);
        float a = acc4[0];
        a = (g == 1) ? acc4[1] : a;
        a = (g == 2) ? acc4[2] : a;
        a = (g == 3) ? acc4[3] : a;
        float wv = We[sl * 4 + g];
        hout[(size_t)node * 64 + sl * 4 + g] += (a + sse * wv) * inv;
    }
}

// ---------------- BatchNorm ----------------
template<int D>
__global__ __launch_bounds__(256) void k_bnstats(const float* __restrict__ h,
                                                 float* __restrict__ sums,
                                                 int rows_per_block) {
    constexpr int NSUB = 256 / D;
    int col = threadIdx.x % D;
    int sub = threadIdx.x / D;
    int r0 = blockIdx.x * rows_per_block;
    int r1 = min(r0 + rows_per_block, NN);
    float s = 0.f, ss = 0.f;
    for (int r = r0 + sub; r < r1; r += NSUB) {
        float x = h[(size_t)r * D + col];
        s += x; ss += x * x;
    }
    atomicAdd(&sums[col], s);
    atomicAdd(&sums[D + col], ss);
}

template<int D>
__global__ void k_bnfin(const float* __restrict__ sums,
                        const float* __restrict__ gamma, const float* __restrict__ beta,
                        float* __restrict__ ab) {
    int c = threadIdx.x;
    if (c >= D) return;
    float mean = sums[c] / (float)NN;
    float var = sums[D + c] / (float)NN - mean * mean;
    float a = gamma[c] * rsqrtf(var + EPS_BN);
    ab[c] = a;
    ab[D + c] = beta[c] - mean * a;
}

__global__ __launch_bounds__(256) void k_bnapply0(float* __restrict__ h,
                                                  const float* __restrict__ ab,
                                                  float* __restrict__ xs,
                                                  ushort* __restrict__ h0b) {
    int idx = blockIdx.x * 256 + threadIdx.x;     // over NN*64 float4s
    int n = idx >> 6, c4 = idx & 63;
    float4 x4 = *reinterpret_cast<float4*>(&h[(size_t)idx * 4]);
    float4 a4 = *reinterpret_cast<const float4*>(&ab[c4 * 4]);
    float4 b4 = *reinterpret_cast<const float4*>(&ab[256 + c4 * 4]);
    float4 r;
    r.x = a4.x * x4.x + b4.x; r.y = a4.y * x4.y + b4.y;
    r.z = a4.z * x4.z + b4.z; r.w = a4.w * x4.w + b4.w;
    *reinterpret_cast<float4*>(&xs[(size_t)n * 320 + c4 * 4]) = r;
    ushort4 o;
    o.x = f2bf(r.x); o.y = f2bf(r.y); o.z = f2bf(r.z); o.w = f2bf(r.w);
    *reinterpret_cast<ushort4*>(&h0b[(size_t)idx * 4]) = o;
}

__global__ __launch_bounds__(256) void k_bnapply1(const float* __restrict__ h,
                                                  const float* __restrict__ ab,
                                                  float* __restrict__ xs) {
    int idx = blockIdx.x * 256 + threadIdx.x;     // over NN*16 float4s
    int n = idx >> 4, c4 = idx & 15;
    float4 x4 = *reinterpret_cast<const float4*>(&h[(size_t)idx * 4]);
    float4 a4 = *reinterpret_cast<const float4*>(&ab[c4 * 4]);
    float4 b4 = *reinterpret_cast<const float4*>(&ab[64 + c4 * 4]);
    float4 r;
    r.x = a4.x * x4.x + b4.x; r.y = a4.y * x4.y + b4.y;
    r.z = a4.z * x4.z + b4.z; r.w = a4.w * x4.w + b4.w;
    *reinterpret_cast<float4*>(&xs[(size_t)n * 320 + 256 + c4 * 4]) = r;
}

// ---------------- global mean pool ----------------
__global__ __launch_bounds__(256) void k_pool(const float* __restrict__ xs,
                                              const int* __restrict__ batch,
                                              float* __restrict__ xpool) {
    int g = blockIdx.x;
    __shared__ int se[2];
    if (threadIdx.x < 2) {
        int target = g + threadIdx.x;
        int lo = 0, hi = NN;
        while (lo < hi) {
            int mid = (lo + hi) >> 1;
            if (batch[mid] < target) lo = mid + 1; else hi = mid;
        }
        se[threadIdx.x] = lo;
    }
    __syncthreads();
    int start = se[0], stop = se[1];
    float cnt = fmaxf((float)(stop - start), 1.0f);
    for (int c = threadIdx.x; c < 320; c += 256) {
        float s = 0.f;
        for (int r = start; r < stop; ++r) s += xs[(size_t)r * 320 + c];
        xpool[(size_t)g * 320 + c] = s / cnt;
    }
}

// ---------------- launch ----------------
extern "C" void kernel_launch(void* const* d_in, const int* in_sizes, int n_in,
                              void* d_out, int out_size, void* d_ws, size_t ws_size,
                              hipStream_t stream) {
    const float* x     = (const float*)d_in[0];
    const int*   ei    = (const int*)d_in[1];
    const float* ea    = (const float*)d_in[2];
    const int*   batch = (const int*)d_in[3];
    const float *Wq0 = (const float*)d_in[4],  *bq0 = (const float*)d_in[5];
    const float *Wk0 = (const float*)d_in[6],  *bk0 = (const float*)d_in[7];
    const float *Wv0 = (const float*)d_in[8],  *bv0 = (const float*)d_in[9];
    const float *We0 = (const float*)d_in[10];
    const float *Ws0 = (const float*)d_in[11], *bs0 = (const float*)d_in[12];
    const float *gamma0 = (const float*)d_in[13], *beta0 = (const float*)d_in[14];
    const float *Wq1 = (const float*)d_in[15], *bq1 = (const float*)d_in[16];
    const float *Wk1 = (const float*)d_in[17], *bk1 = (const float*)d_in[18];
    const float *Wv1 = (const float*)d_in[19], *bv1 = (const float*)d_in[20];
    const float *We1 = (const float*)d_in[21];
    const float *Ws1 = (const float*)d_in[22], *bs1 = (const float*)d_in[23];
    const float *gamma1 = (const float*)d_in[24], *beta1 = (const float*)d_in[25];

    char* ws = (char*)d_ws;
    size_t off = 0;
    auto alloc = [&](size_t bytes) -> char* {
        char* p = ws + off;
        off += (bytes + 255) & ~(size_t)255;
        return p;
    };
    float*  q0   = (float*)alloc((size_t)NN * D0 * 4);   // layer1 q1 aliases
    ushort* kv0  = (ushort*)alloc((size_t)NN * 2 * D0 * 2);  // [NN][512] bf16; layer1 kv1 aliases
    float*  h0   = (float*)alloc((size_t)NN * D0 * 4);   // layer1 h1 aliases
    ushort* xbuf = (ushort*)alloc((size_t)NN * D0 * 2);  // xb (layer0 in) then h0b (layer1 in)
    int2*  sedge = (int2*)alloc((size_t)NE * 8);
    int*   cnt    = (int*)alloc((size_t)(NN + 1) * 4);
    int*   offs   = (int*)alloc((size_t)(NN + 1) * 4);
    int*   cursor = (int*)alloc((size_t)(NN + 1) * 4);
    int*   bsum   = (int*)alloc(256 * 4);
    int*   boff   = (int*)alloc(256 * 4);
    float* sums0  = (float*)alloc(2 * D0 * 4);
    float* ab0    = (float*)alloc(2 * D0 * 4);
    float* sums1  = (float*)alloc(2 * D1 * 4);
    float* ab1    = (float*)alloc(2 * D1 * 4);
    ushort* wt0   = (ushort*)alloc((size_t)4 * D0 * F_IN * 2);  // [1024][128]
    ushort* wt1   = (ushort*)alloc((size_t)4 * D1 * D0 * 2);    // [256][256]

    ushort* xb  = xbuf;                    // [NN][128] bf16
    ushort* h0b = xbuf;                    // [NN][256] bf16 (xb dead by then)

    float*  q1  = q0;
    ushort* kv1 = kv0;                     // [NN][128] bf16
    float*  h1  = h0;

    float* xpool = (float*)d_out;
    float* xs = (float*)d_out + (size_t)NG * 320;

    const int NBLK = (NN + 255) / 256;   // 196
    const int BN_BLK = (NN + 63) / 64;   // 782

    // --- prep ---
    hipMemsetAsync(cnt, 0, (NN + 1) * 4, stream);
    k_hist<<<(NE + 255) / 256, 256, 0, stream>>>(ei, cnt);
    k_scan1<<<NBLK, 256, 0, stream>>>(cnt, offs, bsum);
    k_scan2<<<1, 256, 0, stream>>>(bsum, boff, NBLK);
    k_scan3<<<NBLK, 256, 0, stream>>>(offs, boff, cursor);
    k_scatter<<<(NE + 255) / 256, 256, 0, stream>>>(ei, ea, cursor, sedge);

    k_f2bf4<<<2048, 256, 0, stream>>>(x, xb, NN * F_IN / 4);
    WPrep wp;
    wp.src[0] = Wq0; wp.src[1] = Wk0; wp.src[2] = Wv0; wp.src[3] = Ws0;
    wp.src[4] = Wq1; wp.src[5] = Wk1; wp.src[6] = Wv1; wp.src[7] = Ws1;
    for (int m = 0; m < 4; ++m) { wp.K[m] = F_IN; wp.D[m] = D0; wp.dst[m] = wt0 + (size_t)m * D0 * F_IN; }
    for (int m = 0; m < 4; ++m) { wp.K[4+m] = D0; wp.D[4+m] = D1; wp.dst[4+m] = wt1 + (size_t)m * D1 * D0; }
    k_wprep<<<dim3(64, 8), 256, 0, stream>>>(wp);

    // --- layer 0 ---
    k_gemm_mfma<F_IN, D0><<<dim3((NN + 127) / 128, 16), 256, 0, stream>>>(
        xb, wt0, bq0, bk0, bv0, bs0, q0, kv0, h0);
    k_attn<D0><<<(NN + 3) / 4, 256, 0, stream>>>(q0, kv0, We0, sedge, offs, h0);
    hipMemsetAsync(sums0, 0, 2 * D0 * 4, stream);
    k_bnstats<D0><<<BN_BLK, 256, 0, stream>>>(h0, sums0, 64);
    k_bnfin<D0><<<1, D0, 0, stream>>>(sums0, gamma0, beta0, ab0);
    k_bnapply0<<<(NN * 64 + 255) / 256, 256, 0, stream>>>(h0, ab0, xs, h0b);

    // --- layer 1 ---
    k_gemm_mfma<D0, D1><<<dim3((NN + 127) / 128, 4), 256, 0, stream>>>(
        h0b, wt1, bq1, bk1, bv1, bs1, q1, kv1, h1);
    k_attn<D1><<<(NN + 3) / 4, 256, 0, stream>>>(q1, kv1, We1, sedge, offs, h1);
    hipMemsetAsync(sums1, 0, 2 * D1 * 4, stream);
    k_bnstats<D1><<<BN_BLK, 256, 0, stream>>>(h1, sums1, 64);
    k_bnfin<D1><<<1, D1, 0, stream>>>(sums1, gamma1, beta1, ab1);
    k_bnapply1<<<(NN * 16 + 255) / 256, 256, 0, stream>>>(h1, ab1, xs);

    // --- pool ---
    k_pool<<<NG, 256, 0, stream>>>(xs, batch, xpool);
}

// Round 6
// 758.439 us; speedup vs baseline: 1.0290x; 1.0290x over previous
//
#include <hip/hip_runtime.h>

// Problem constants (match reference)
constexpr int NN = 50000;      // nodes
constexpr int NE = 800000;     // edges
constexpr int F_IN = 128;
constexpr int D0 = 256;
constexpr int D1 = 64;
constexpr int NG = 256;        // graphs
constexpr float EPS_BN = 1e-5f;

typedef __attribute__((ext_vector_type(8))) short bf16x8;
typedef __attribute__((ext_vector_type(4))) float f32x4;
typedef __attribute__((ext_vector_type(8))) ushort u16x8;
typedef __attribute__((ext_vector_type(4))) ushort u16x4;

__device__ inline ushort f2bf(float f) {
    uint32_t u = __float_as_uint(f);
    uint32_t r = u + 0x7fff + ((u >> 16) & 1);   // RNE
    return (ushort)(r >> 16);
}
__device__ inline float bf2f(ushort b) {
    return __uint_as_float((uint32_t)b << 16);
}

// ---------------- edge sort (counting sort by dst) ----------------
__global__ __launch_bounds__(256) void k_hist(const int* __restrict__ ei, int* __restrict__ cnt) {
    int e = blockIdx.x * 256 + threadIdx.x;
    if (e < NE) atomicAdd(&cnt[ei[NE + e]], 1);
}

__global__ __launch_bounds__(256) void k_scan1(const int* __restrict__ cnt,
                                               int* __restrict__ offs,
                                               int* __restrict__ bsum) {
    __shared__ int lds[256];
    int idx = blockIdx.x * 256 + threadIdx.x;
    int v = (idx < NN) ? cnt[idx] : 0;
    lds[threadIdx.x] = v;
    __syncthreads();
    #pragma unroll
    for (int off = 1; off < 256; off <<= 1) {
        int add = (threadIdx.x >= off) ? lds[threadIdx.x - off] : 0;
        __syncthreads();
        lds[threadIdx.x] += add;
        __syncthreads();
    }
    if (idx < NN) offs[idx] = lds[threadIdx.x] - v;
    if (threadIdx.x == 255) bsum[blockIdx.x] = lds[255];
}

__global__ __launch_bounds__(256) void k_scan2(const int* __restrict__ bsum,
                                               int* __restrict__ boff, int nblk) {
    __shared__ int lds[256];
    int v = (threadIdx.x < nblk) ? bsum[threadIdx.x] : 0;
    lds[threadIdx.x] = v;
    __syncthreads();
    #pragma unroll
    for (int off = 1; off < 256; off <<= 1) {
        int add = (threadIdx.x >= off) ? lds[threadIdx.x - off] : 0;
        __syncthreads();
        lds[threadIdx.x] += add;
        __syncthreads();
    }
    if (threadIdx.x < nblk) boff[threadIdx.x] = lds[threadIdx.x] - v;
}

__global__ __launch_bounds__(256) void k_scan3(int* __restrict__ offs,
                                               const int* __restrict__ boff,
                                               int* __restrict__ cursor) {
    int idx = blockIdx.x * 256 + threadIdx.x;
    if (idx < NN) {
        int o = offs[idx] + boff[blockIdx.x];
        offs[idx] = o;
        cursor[idx] = o;
    }
    if (idx == 0) offs[NN] = NE;
}

// pack (src, edge_attr bits) per sorted edge
__global__ __launch_bounds__(256) void k_scatter(const int* __restrict__ ei,
                                                 const float* __restrict__ ea,
                                                 int* __restrict__ cursor,
                                                 int2* __restrict__ sedge) {
    int e = blockIdx.x * 256 + threadIdx.x;
    if (e < NE) {
        int d = ei[NE + e];
        int pos = atomicAdd(&cursor[d], 1);
        sedge[pos] = make_int2(ei[e], __float_as_int(ea[e]));
    }
}

// ---------------- prep: fp32 -> bf16 cast (vectorized) ----------------
__global__ __launch_bounds__(256) void k_f2bf4(const float* __restrict__ in,
                                               ushort* __restrict__ out, int n4) {
    for (int i = blockIdx.x * 256 + threadIdx.x; i < n4; i += gridDim.x * 256) {
        float4 v = *reinterpret_cast<const float4*>(&in[(size_t)i * 4]);
        ushort4 o;
        o.x = f2bf(v.x); o.y = f2bf(v.y); o.z = f2bf(v.z); o.w = f2bf(v.w);
        *reinterpret_cast<ushort4*>(&out[(size_t)i * 4]) = o;
    }
}

// ---------------- prep: LDS-tiled weight transpose + bf16 ([K][D] -> [D][K]) ----------------
struct WPrep {
    const float* src[8];
    ushort* dst[8];
    int K[8];
    int D[8];
};
__global__ __launch_bounds__(256) void k_wprep(WPrep p) {
    int m = blockIdx.y;
    int K = p.K[m], D = p.D[m];
    int ntx = K >> 5, nty = D >> 5;
    int tile = blockIdx.x;
    if (tile >= ntx * nty) return;
    int tk = (tile % ntx) << 5;
    int tc = (tile / ntx) << 5;
    __shared__ ushort lds[32][33];
    int tx = threadIdx.x & 31, ty = threadIdx.x >> 5;   // 8 rows per pass
    const float* src = p.src[m];
    ushort* dst = p.dst[m];
    #pragma unroll
    for (int i = 0; i < 4; ++i) {
        int k = tk + ty + i * 8;
        lds[ty + i * 8][tx] = f2bf(src[(size_t)k * D + tc + tx]);
    }
    __syncthreads();
    #pragma unroll
    for (int i = 0; i < 4; ++i) {
        int c = tc + ty + i * 8;
        dst[(size_t)c * K + tk + tx] = lds[tx][ty + i * 8];
    }
}

// ---------------- fused 4-matrix MFMA GEMM ----------------
// mat0 -> Oqb (bf16); mat1/2 -> kv (bf16; DOUT=256: [k|v] halves, DOUT=64: 4-dim interleave);
// mat3 -> Oh (fp32).
template<int K, int DOUT, int BN>
__global__ __launch_bounds__(256) void k_gemm_mfma(
    const ushort* __restrict__ Xb, const ushort* __restrict__ Wt,
    const float* __restrict__ B0, const float* __restrict__ B1,
    const float* __restrict__ B2, const float* __restrict__ B3,
    ushort* __restrict__ Oqb, ushort* __restrict__ Okv,
    float* __restrict__ Oh)
{
    constexpr int BM = 128, BK = 32;
    constexpr int NB = BN / 32;                  // B-frags per wave (wave covers BN/2 cols)
    __shared__ ushort Xs[BM][BK + 8];
    __shared__ ushort Wss[BN][BK + 8];

    int row0 = blockIdx.x * BM;
    int col0 = blockIdx.y * BN;
    int mat = col0 / DOUT;
    int mcol0 = col0 - mat * DOUT;
    const float* Bb = (mat == 0) ? B0 : (mat == 1) ? B1 : (mat == 2) ? B2 : B3;

    int t = threadIdx.x;
    int wid = t >> 6, lane = t & 63;
    int wr = wid >> 1, wc = wid & 1;
    int lr = lane & 15, lk = lane >> 4;

    f32x4 acc[4][NB] = {};

    for (int k0 = 0; k0 < K; k0 += BK) {
        #pragma unroll
        for (int i = 0; i < 2; ++i) {            // X tile: 128x32 = 512 slots
            int slot = t + i * 256;
            int r = slot >> 2, c8 = slot & 3;
            int gr = row0 + r;
            uint4 val = make_uint4(0, 0, 0, 0);
            if (gr < NN) val = *reinterpret_cast<const uint4*>(&Xb[(size_t)gr * K + k0 + c8 * 8]);
            *reinterpret_cast<uint4*>(&Xs[r][c8 * 8]) = val;
        }
        #pragma unroll
        for (int i = 0; i < (BN * 4) / 256; ++i) {   // W tile: BNx32
            int slot = t + i * 256;
            int r = slot >> 2, c8 = slot & 3;
            uint4 val = *reinterpret_cast<const uint4*>(&Wt[(size_t)(col0 + r) * K + k0 + c8 * 8]);
            *reinterpret_cast<uint4*>(&Wss[r][c8 * 8]) = val;
        }
        __syncthreads();
        bf16x8 a[4], b[NB];
        #pragma unroll
        for (int m = 0; m < 4; ++m)
            a[m] = *reinterpret_cast<const bf16x8*>(&Xs[wr * 64 + m * 16 + lr][lk * 8]);
        #pragma unroll
        for (int n = 0; n < NB; ++n)
            b[n] = *reinterpret_cast<const bf16x8*>(&Wss[wc * (BN / 2) + n * 16 + lr][lk * 8]);
        #pragma unroll
        for (int m = 0; m < 4; ++m)
            #pragma unroll
            for (int n = 0; n < NB; ++n)
                acc[m][n] = __builtin_amdgcn_mfma_f32_16x16x32_bf16(a[m], b[n], acc[m][n], 0, 0, 0);
        __syncthreads();
    }

    // epilogue: C/D layout col=lane&15, row=(lane>>4)*4+reg
    #pragma unroll
    for (int m = 0; m < 4; ++m) {
        #pragma unroll
        for (int n = 0; n < NB; ++n) {
            int gcol = mcol0 + wc * (BN / 2) + n * 16 + lr;
            float bias = Bb[gcol];
            #pragma unroll
            for (int r = 0; r < 4; ++r) {
                int grow = row0 + wr * 64 + m * 16 + lk * 4 + r;
                if (grow >= NN) continue;
                float vv = acc[m][n][r] + bias;
                if (mat == 0) {
                    Oqb[(size_t)grow * DOUT + gcol] = f2bf(vv);
                } else if (mat == 3) {
                    Oh[(size_t)grow * DOUT + gcol] = vv;
                } else if (DOUT == 256) {
                    // [k(256) | v(256)] contiguous halves
                    Okv[(size_t)grow * 512 + (mat == 2 ? 256 : 0) + gcol] = f2bf(vv);
                } else {
                    // 4-dim interleave: chunk c = gcol>>2: {k4 | v4} per 16B
                    Okv[(size_t)grow * 128 + ((gcol >> 2) << 3) + (mat == 2 ? 4 : 0) + (gcol & 3)] = f2bf(vv);
                }
            }
        }
    }
}

// ---------------- per-node attention: single pass, factored edge term ----------------
// logits = (q.k + e*(q.We)) * scale ; out = (sum p*v + (sum p*e)*We) / sum p
// D=256: 2 groups x 32 lanes (8 dims); D=64: 4 groups x 16 lanes (4 dims, one 16B kv load).
// 3-stage rotating register pipeline (2 prefetches in flight).
template<int D>
__global__ __launch_bounds__(256) void k_attn(
    const ushort* __restrict__ qb, const ushort* __restrict__ kvb,
    const float* __restrict__ We,
    const int2* __restrict__ sedge,
    const int* __restrict__ offs,
    float* __restrict__ hout)               // pre-loaded with skip; += attn out
{
    int wave = threadIdx.x >> 6;
    int lane = threadIdx.x & 63;
    int node = blockIdx.x * 4 + wave;
    if (node >= NN) return;
    int start = offs[node], stop = offs[node + 1];

    if constexpr (D == 256) {
        constexpr float scale = 0.0625f;
        int g = lane >> 5, sl = lane & 31;
        float q8[8], wel8[8];
        {
            u16x8 qu = *reinterpret_cast<const u16x8*>(&qb[(size_t)node * 256 + sl * 8]);
            #pragma unroll
            for (int c = 0; c < 8; ++c) q8[c] = bf2f((ushort)qu[c]);
            float4 wa = *reinterpret_cast<const float4*>(&We[sl * 8]);
            float4 wb = *reinterpret_cast<const float4*>(&We[sl * 8 + 4]);
            wel8[0] = wa.x; wel8[1] = wa.y; wel8[2] = wa.z; wel8[3] = wa.w;
            wel8[4] = wb.x; wel8[5] = wb.y; wel8[6] = wb.z; wel8[7] = wb.w;
        }
        float qWe = 0.f;
        #pragma unroll
        for (int c = 0; c < 8; ++c) qWe = fmaf(q8[c], wel8[c], qWe);
        #pragma unroll
        for (int o = 1; o <= 16; o <<= 1) qWe += __shfl_xor(qWe, o);

        int niter = (stop - start + 1) >> 1;
        float acc8[8] = {};
        float ssum = 0.f, sse = 0.f;

        bool val0, val1; int2 se0, se1;
        u16x8 ku0, vu0, ku1, vu1;
        auto LOAD = [&](int j, bool& val, int2& se, u16x8& ku, u16x8& vu) {
            int idx = start + 2 * j + g;
            val = idx < stop;
            int e = val ? idx : 0;
            se = sedge[e];
            const ushort* base = &kvb[(size_t)se.x * 512 + sl * 8];
            ku = *reinterpret_cast<const u16x8*>(base);
            vu = *reinterpret_cast<const u16x8*>(base + 256);
        };
        LOAD(0, val0, se0, ku0, vu0);
        LOAD(1, val1, se1, ku1, vu1);

        for (int j = 0; j < niter; ++j) {
            bool val2; int2 se2; u16x8 ku2, vu2;
            LOAD(j + 2, val2, se2, ku2, vu2);
            float dot = 0.f;
            #pragma unroll
            for (int c = 0; c < 8; ++c) dot = fmaf(q8[c], bf2f((ushort)ku0[c]), dot);
            #pragma unroll
            for (int o = 1; o <= 16; o <<= 1) dot += __shfl_xor(dot, o);
            float eav = __int_as_float(se0.y);
            float p = val0 ? __expf((dot + eav * qWe) * scale) : 0.f;
            ssum += p;
            sse = fmaf(p, eav, sse);
            #pragma unroll
            for (int c = 0; c < 8; ++c) acc8[c] = fmaf(p, bf2f((ushort)vu0[c]), acc8[c]);
            val0 = val1; se0 = se1; ku0 = ku1; vu0 = vu1;
            val1 = val2; se1 = se2; ku1 = ku2; vu1 = vu2;
        }
        #pragma unroll
        for (int c = 0; c < 8; ++c) acc8[c] = fmaf(sse, wel8[c], acc8[c]);
        // combine the two halves
        ssum += __shfl_xor(ssum, 32);
        #pragma unroll
        for (int c = 0; c < 8; ++c) acc8[c] += __shfl_xor(acc8[c], 32);
        float inv = 1.0f / (ssum + 1e-16f);
        float o4[4];
        #pragma unroll
        for (int c = 0; c < 4; ++c) o4[c] = g ? acc8[4 + c] : acc8[c];
        float* hp = &hout[(size_t)node * 256 + sl * 8 + g * 4];
        float4 cur = *reinterpret_cast<float4*>(hp);
        cur.x += o4[0] * inv; cur.y += o4[1] * inv;
        cur.z += o4[2] * inv; cur.w += o4[3] * inv;
        *reinterpret_cast<float4*>(hp) = cur;
    } else {
        constexpr float scale = 0.125f;
        int g = lane >> 4, sl = lane & 15;
        float q4[4], wel4[4];
        {
            ushort4 qu = *reinterpret_cast<const ushort4*>(&qb[(size_t)node * 64 + sl * 4]);
            q4[0] = bf2f(qu.x); q4[1] = bf2f(qu.y); q4[2] = bf2f(qu.z); q4[3] = bf2f(qu.w);
            float4 wa = *reinterpret_cast<const float4*>(&We[sl * 4]);
            wel4[0] = wa.x; wel4[1] = wa.y; wel4[2] = wa.z; wel4[3] = wa.w;
        }
        float qWe = 0.f;
        #pragma unroll
        for (int c = 0; c < 4; ++c) qWe = fmaf(q4[c], wel4[c], qWe);
        #pragma unroll
        for (int o = 1; o <= 8; o <<= 1) qWe += __shfl_xor(qWe, o);

        int niter = (stop - start + 3) >> 2;
        float acc4[4] = {};
        float ssum = 0.f, sse = 0.f;

        bool val0, val1; int2 se0, se1;
        u16x8 kv0r, kv1r;
        auto LOAD = [&](int j, bool& val, int2& se, u16x8& kv) {
            int idx = start + 4 * j + g;
            val = idx < stop;
            int e = val ? idx : 0;
            se = sedge[e];
            kv = *reinterpret_cast<const u16x8*>(&kvb[(size_t)se.x * 128 + sl * 8]);
        };
        LOAD(0, val0, se0, kv0r);
        LOAD(1, val1, se1, kv1r);

        for (int j = 0; j < niter; ++j) {
            bool val2; int2 se2; u16x8 kv2r;
            LOAD(j + 2, val2, se2, kv2r);
            float dot = 0.f;
            #pragma unroll
            for (int c = 0; c < 4; ++c) dot = fmaf(q4[c], bf2f((ushort)kv0r[c]), dot);
            #pragma unroll
            for (int o = 1; o <= 8; o <<= 1) dot += __shfl_xor(dot, o);
            float eav = __int_as_float(se0.y);
            float p = val0 ? __expf((dot + eav * qWe) * scale) : 0.f;
            ssum += p;
            sse = fmaf(p, eav, sse);
            #pragma unroll
            for (int c = 0; c < 4; ++c) acc4[c] = fmaf(p, bf2f((ushort)kv0r[4 + c]), acc4[c]);
            val0 = val1; se0 = se1; kv0r = kv1r;
            val1 = val2; se1 = se2; kv1r = kv2r;
        }
        #pragma unroll
        for (int c = 0; c < 4; ++c) acc4[c] = fmaf(sse, wel4[c], acc4[c]);
        ssum += __shfl_xor(ssum, 16); ssum += __shfl_xor(ssum, 32);
        #pragma unroll
        for (int c = 0; c < 4; ++c) {
            acc4[c] += __shfl_xor(acc4[c], 16);
            acc4[c] += __shfl_xor(acc4[c], 32);
        }
        float inv = 1.0f / (ssum + 1e-16f);
        float a = acc4[0];
        a = (g == 1) ? acc4[1] : a;
        a = (g == 2) ? acc4[2] : a;
        a = (g == 3) ? acc4[3] : a;
        hout[(size_t)node * 64 + sl * 4 + g] += a * inv;
    }
}

// ---------------- BatchNorm ----------------
template<int D>
__global__ __launch_bounds__(256) void k_bnstats(const float* __restrict__ h,
                                                 float* __restrict__ sums,
                                                 int rows_per_block) {
    constexpr int NSUB = 256 / D;
    int col = threadIdx.x % D;
    int sub = threadIdx.x / D;
    int r0 = blockIdx.x * rows_per_block;
    int r1 = min(r0 + rows_per_block, NN);
    float s = 0.f, ss = 0.f;
    for (int r = r0 + sub; r < r1; r += NSUB) {
        float x = h[(size_t)r * D + col];
        s += x; ss += x * x;
    }
    atomicAdd(&sums[col], s);
    atomicAdd(&sums[D + col], ss);
}

template<int D>
__global__ void k_bnfin(const float* __restrict__ sums,
                        const float* __restrict__ gamma, const float* __restrict__ beta,
                        float* __restrict__ ab) {
    int c = threadIdx.x;
    if (c >= D) return;
    float mean = sums[c] / (float)NN;
    float var = sums[D + c] / (float)NN - mean * mean;
    float a = gamma[c] * rsqrtf(var + EPS_BN);
    ab[c] = a;
    ab[D + c] = beta[c] - mean * a;
}

__global__ __launch_bounds__(256) void k_bnapply0(float* __restrict__ h,
                                                  const float* __restrict__ ab,
                                                  float* __restrict__ xs,
                                                  ushort* __restrict__ h0b) {
    int idx = blockIdx.x * 256 + threadIdx.x;     // over NN*64 float4s
    int n = idx >> 6, c4 = idx & 63;
    float4 x4 = *reinterpret_cast<float4*>(&h[(size_t)idx * 4]);
    float4 a4 = *reinterpret_cast<const float4*>(&ab[c4 * 4]);
    float4 b4 = *reinterpret_cast<const float4*>(&ab[256 + c4 * 4]);
    float4 r;
    r.x = a4.x * x4.x + b4.x; r.y = a4.y * x4.y + b4.y;
    r.z = a4.z * x4.z + b4.z; r.w = a4.w * x4.w + b4.w;
    *reinterpret_cast<float4*>(&xs[(size_t)n * 320 + c4 * 4]) = r;
    ushort4 o;
    o.x = f2bf(r.x); o.y = f2bf(r.y); o.z = f2bf(r.z); o.w = f2bf(r.w);
    *reinterpret_cast<ushort4*>(&h0b[(size_t)idx * 4]) = o;
}

__global__ __launch_bounds__(256) void k_bnapply1(const float* __restrict__ h,
                                                  const float* __restrict__ ab,
                                                  float* __restrict__ xs) {
    int idx = blockIdx.x * 256 + threadIdx.x;     // over NN*16 float4s
    int n = idx >> 4, c4 = idx & 15;
    float4 x4 = *reinterpret_cast<const float4*>(&h[(size_t)idx * 4]);
    float4 a4 = *reinterpret_cast<const float4*>(&ab[c4 * 4]);
    float4 b4 = *reinterpret_cast<const float4*>(&ab[64 + c4 * 4]);
    float4 r;
    r.x = a4.x * x4.x + b4.x; r.y = a4.y * x4.y + b4.y;
    r.z = a4.z * x4.z + b4.z; r.w = a4.w * x4.w + b4.w;
    *reinterpret_cast<float4*>(&xs[(size_t)n * 320 + 256 + c4 * 4]) = r;
}

// ---------------- global mean pool ----------------
__global__ __launch_bounds__(256) void k_pool(const float* __restrict__ xs,
                                              const int* __restrict__ batch,
                                              float* __restrict__ xpool) {
    int g = blockIdx.x;
    __shared__ int se[2];
    if (threadIdx.x < 2) {
        int target = g + threadIdx.x;
        int lo = 0, hi = NN;
        while (lo < hi) {
            int mid = (lo + hi) >> 1;
            if (batch[mid] < target) lo = mid + 1; else hi = mid;
        }
        se[threadIdx.x] = lo;
    }
    __syncthreads();
    int start = se[0], stop = se[1];
    float cnt = fmaxf((float)(stop - start), 1.0f);
    for (int c = threadIdx.x; c < 320; c += 256) {
        float s = 0.f;
        for (int r = start; r < stop; ++r) s += xs[(size_t)r * 320 + c];
        xpool[(size_t)g * 320 + c] = s / cnt;
    }
}

// ---------------- launch ----------------
extern "C" void kernel_launch(void* const* d_in, const int* in_sizes, int n_in,
                              void* d_out, int out_size, void* d_ws, size_t ws_size,
                              hipStream_t stream) {
    const float* x     = (const float*)d_in[0];
    const int*   ei    = (const int*)d_in[1];
    const float* ea    = (const float*)d_in[2];
    const int*   batch = (const int*)d_in[3];
    const float *Wq0 = (const float*)d_in[4],  *bq0 = (const float*)d_in[5];
    const float *Wk0 = (const float*)d_in[6],  *bk0 = (const float*)d_in[7];
    const float *Wv0 = (const float*)d_in[8],  *bv0 = (const float*)d_in[9];
    const float *We0 = (const float*)d_in[10];
    const float *Ws0 = (const float*)d_in[11], *bs0 = (const float*)d_in[12];
    const float *gamma0 = (const float*)d_in[13], *beta0 = (const float*)d_in[14];
    const float *Wq1 = (const float*)d_in[15], *bq1 = (const float*)d_in[16];
    const float *Wk1 = (const float*)d_in[17], *bk1 = (const float*)d_in[18];
    const float *Wv1 = (const float*)d_in[19], *bv1 = (const float*)d_in[20];
    const float *We1 = (const float*)d_in[21];
    const float *Ws1 = (const float*)d_in[22], *bs1 = (const float*)d_in[23];
    const float *gamma1 = (const float*)d_in[24], *beta1 = (const float*)d_in[25];

    char* ws = (char*)d_ws;
    size_t off = 0;
    auto alloc = [&](size_t bytes) -> char* {
        char* p = ws + off;
        off += (bytes + 255) & ~(size_t)255;
        return p;
    };
    ushort* qb0  = (ushort*)alloc((size_t)NN * D0 * 2);      // layer1 qb1 aliases
    ushort* kv0  = (ushort*)alloc((size_t)NN * 2 * D0 * 2);  // [NN][512] bf16; layer1 kvi1 aliases
    float*  h0   = (float*)alloc((size_t)NN * D0 * 4);       // layer1 h1 aliases
    ushort* xbuf = (ushort*)alloc((size_t)NN * D0 * 2);      // xb (layer0 in) then h0b (layer1 in)
    int2*  sedge = (int2*)alloc((size_t)NE * 8);
    int*   cnt    = (int*)alloc((size_t)(NN + 1) * 4);
    int*   offs   = (int*)alloc((size_t)(NN + 1) * 4);
    int*   cursor = (int*)alloc((size_t)(NN + 1) * 4);
    int*   bsum   = (int*)alloc(256 * 4);
    int*   boff   = (int*)alloc(256 * 4);
    float* sums0  = (float*)alloc(2 * D0 * 4);
    float* ab0    = (float*)alloc(2 * D0 * 4);
    float* sums1  = (float*)alloc(2 * D1 * 4);
    float* ab1    = (float*)alloc(2 * D1 * 4);
    ushort* wt0   = (ushort*)alloc((size_t)4 * D0 * F_IN * 2);  // [1024][128]
    ushort* wt1   = (ushort*)alloc((size_t)4 * D1 * D0 * 2);    // [256][256]

    ushort* xb  = xbuf;                    // [NN][128] bf16
    ushort* h0b = xbuf;                    // [NN][256] bf16 (xb dead by then)

    ushort* qb1 = qb0;                     // [NN][64] bf16
    ushort* kvi1 = kv0;                    // [NN][128] bf16 interleaved {k4|v4}
    float*  h1  = h0;

    float* xpool = (float*)d_out;
    float* xs = (float*)d_out + (size_t)NG * 320;

    const int NBLK = (NN + 255) / 256;   // 196
    const int BN_BLK = (NN + 63) / 64;   // 782

    // --- prep ---
    hipMemsetAsync(cnt, 0, (NN + 1) * 4, stream);
    k_hist<<<(NE + 255) / 256, 256, 0, stream>>>(ei, cnt);
    k_scan1<<<NBLK, 256, 0, stream>>>(cnt, offs, bsum);
    k_scan2<<<1, 256, 0, stream>>>(bsum, boff, NBLK);
    k_scan3<<<NBLK, 256, 0, stream>>>(offs, boff, cursor);
    k_scatter<<<(NE + 255) / 256, 256, 0, stream>>>(ei, ea, cursor, sedge);

    k_f2bf4<<<2048, 256, 0, stream>>>(x, xb, NN * F_IN / 4);
    WPrep wp;
    wp.src[0] = Wq0; wp.src[1] = Wk0; wp.src[2] = Wv0; wp.src[3] = Ws0;
    wp.src[4] = Wq1; wp.src[5] = Wk1; wp.src[6] = Wv1; wp.src[7] = Ws1;
    for (int m = 0; m < 4; ++m) { wp.K[m] = F_IN; wp.D[m] = D0; wp.dst[m] = wt0 + (size_t)m * D0 * F_IN; }
    for (int m = 0; m < 4; ++m) { wp.K[4+m] = D0; wp.D[4+m] = D1; wp.dst[4+m] = wt1 + (size_t)m * D1 * D0; }
    k_wprep<<<dim3(32, 8), 256, 0, stream>>>(wp);

    // --- layer 0 ---
    k_gemm_mfma<F_IN, D0, 128><<<dim3((NN + 127) / 128, 8), 256, 0, stream>>>(
        xb, wt0, bq0, bk0, bv0, bs0, qb0, kv0, h0);
    k_attn<D0><<<(NN + 3) / 4, 256, 0, stream>>>(qb0, kv0, We0, sedge, offs, h0);
    hipMemsetAsync(sums0, 0, 2 * D0 * 4, stream);
    k_bnstats<D0><<<BN_BLK, 256, 0, stream>>>(h0, sums0, 64);
    k_bnfin<D0><<<1, D0, 0, stream>>>(sums0, gamma0, beta0, ab0);
    k_bnapply0<<<(NN * 64 + 255) / 256, 256, 0, stream>>>(h0, ab0, xs, h0b);

    // --- layer 1 ---
    k_gemm_mfma<D0, D1, 64><<<dim3((NN + 127) / 128, 4), 256, 0, stream>>>(
        h0b, wt1, bq1, bk1, bv1, bs1, qb1, kvi1, h1);
    k_attn<D1><<<(NN + 3) / 4, 256, 0, stream>>>(qb1, kvi1, We1, sedge, offs, h1);
    hipMemsetAsync(sums1, 0, 2 * D1 * 4, stream);
    k_bnstats<D1><<<BN_BLK, 256, 0, stream>>>(h1, sums1, 64);
    k_bnfin<D1><<<1, D1, 0, stream>>>(sums1, gamma1, beta1, ab1);
    k_bnapply1<<<(NN * 16 + 255) / 256, 256, 0, stream>>>(h1, ab1, xs);

    // --- pool ---
    k_pool<<<NG, 256, 0, stream>>>(xs, batch, xpool);
}